// Round 1
// baseline (836.757 us; speedup 1.0000x reference)
//
#include <hip/hip_runtime.h>

#define N_NODES 50000
#define N_EDGES 800000
#define FEAT 128
#define PART 32
#define NP 50048          // N padded to multiple of 64
#define SCAN_NB 196       // ceil(N/256)

// ---------------- init ----------------
__global__ void k_init(float* deg, int* cnt, int* fill, float* colsum, float* colsumsq,
                       float* out_head) {
    int i = blockIdx.x * 256 + threadIdx.x;
    if (i < N_NODES) deg[i] = 1.0f;          // self-loop weight
    if (i < NP) { cnt[i] = 0; fill[i] = 0; }
    if (i < 128) { colsum[i] = 0.f; colsumsq[i] = 0.f; }
    if (i < 32) out_head[i] = 0.f;
}

// ---------------- degree ----------------
__global__ void k_deg(const int* __restrict__ dst, const float* __restrict__ w, float* deg) {
    int e = blockIdx.x * 256 + threadIdx.x;
    if (e < N_EDGES) unsafeAtomicAdd(&deg[dst[e]], w[e]);
}

__global__ void k_dinv(const float* __restrict__ deg, float* dinv, float* selfn) {
    int i = blockIdx.x * 256 + threadIdx.x;
    if (i < N_NODES) {
        float d = rsqrtf(deg[i]);
        dinv[i] = d;
        selfn[i] = d * d;
    }
}

__global__ void k_normcnt(const int* __restrict__ src, const int* __restrict__ dst,
                          const float* __restrict__ w, const float* __restrict__ dinv,
                          float* normv, int* cnt) {
    int e = blockIdx.x * 256 + threadIdx.x;
    if (e < N_EDGES) {
        int s = src[e], d = dst[e];
        normv[e] = dinv[s] * w[e] * dinv[d];
        atomicAdd(&cnt[d], 1);
    }
}

// ---------------- scan (exclusive prefix over cnt) ----------------
__global__ void k_scan_partial(const int* __restrict__ cnt, int* bsum) {
    __shared__ int s[256];
    int t = threadIdx.x;
    int i = blockIdx.x * 256 + t;
    s[t] = (i < N_NODES) ? cnt[i] : 0;
    __syncthreads();
    for (int d = 128; d; d >>= 1) { if (t < d) s[t] += s[t + d]; __syncthreads(); }
    if (t == 0) bsum[blockIdx.x] = s[0];
}

__global__ void k_scan_mid(int* bsum) {
    __shared__ int s[256];
    int t = threadIdx.x;
    s[t] = (t < SCAN_NB) ? bsum[t] : 0;
    __syncthreads();
    if (t == 0) {
        int run = 0;
        for (int b = 0; b < SCAN_NB; ++b) { int v = s[b]; s[b] = run; run += v; }
    }
    __syncthreads();
    if (t < SCAN_NB) bsum[t] = s[t];
}

__global__ void k_scan_final(const int* __restrict__ cnt, const int* __restrict__ bsum, int* offs) {
    __shared__ int s[256];
    int t = threadIdx.x;
    int i = blockIdx.x * 256 + t;
    int v = (i < N_NODES) ? cnt[i] : 0;
    s[t] = v;
    __syncthreads();
    for (int d = 1; d < 256; d <<= 1) {
        int tv = (t >= d) ? s[t - d] : 0;
        __syncthreads();
        s[t] += tv;
        __syncthreads();
    }
    if (i < N_NODES) offs[i] = bsum[blockIdx.x] + s[t] - v;
}

__global__ void k_fill(const int* __restrict__ src, const int* __restrict__ dst,
                       const float* __restrict__ normv, const int* __restrict__ offs,
                       int* fill, int* es, float* en) {
    int e = blockIdx.x * 256 + threadIdx.x;
    if (e >= N_EDGES) return;
    int d = dst[e];
    int pos = offs[d] + atomicAdd(&fill[d], 1);
    es[pos] = src[e];
    en[pos] = normv[e];
}

// ---------------- GEMM: C[n,0:128] = A[n,0:128] @ W[128,128] + bias ----------------
__global__ __launch_bounds__(256) void k_gemm(const float* __restrict__ A,
                                              const float* __restrict__ W,
                                              const float* __restrict__ bias,
                                              float* __restrict__ C, int nrows) {
    __shared__ float Ws[128 * 128];
    __shared__ float As[32 * 128];
    int t = threadIdx.x;
    const float4* W4 = (const float4*)W;
    float4* Ws4s = (float4*)Ws;
    for (int i = t; i < 128 * 32; i += 256) Ws4s[i] = W4[i];
    int rowBase = blockIdx.x * 32;
    const float4* A4 = (const float4*)A;
    float4* As4s = (float4*)As;
    for (int i = t; i < 32 * 32; i += 256) {
        int r = i >> 5, c = i & 31;
        int gr = rowBase + r;
        As4s[i] = (gr < nrows) ? A4[(size_t)gr * 32 + c] : make_float4(0.f, 0.f, 0.f, 0.f);
    }
    __syncthreads();
    int tc = t & 31;   // cols tc*4 .. +3
    int tr = t >> 5;   // rows tr*4 .. +3
    float acc[4][4] = {};
    const float4* Ws4 = (const float4*)Ws;
    const float4* As4 = (const float4*)As;
    for (int k = 0; k < 128; k += 4) {
        float4 w0 = Ws4[(k + 0) * 32 + tc];
        float4 w1 = Ws4[(k + 1) * 32 + tc];
        float4 w2 = Ws4[(k + 2) * 32 + tc];
        float4 w3 = Ws4[(k + 3) * 32 + tc];
#pragma unroll
        for (int i = 0; i < 4; ++i) {
            float4 a = As4[(tr * 4 + i) * 32 + (k >> 2)];
            acc[i][0] += a.x * w0.x + a.y * w1.x + a.z * w2.x + a.w * w3.x;
            acc[i][1] += a.x * w0.y + a.y * w1.y + a.z * w2.y + a.w * w3.y;
            acc[i][2] += a.x * w0.z + a.y * w1.z + a.z * w2.z + a.w * w3.z;
            acc[i][3] += a.x * w0.w + a.y * w1.w + a.z * w2.w + a.w * w3.w;
        }
    }
    float4 b4 = ((const float4*)bias)[tc];
#pragma unroll
    for (int i = 0; i < 4; ++i) {
        int gr = rowBase + tr * 4 + i;
        if (gr < nrows) {
            float4 o;
            o.x = acc[i][0] + b4.x; o.y = acc[i][1] + b4.y;
            o.z = acc[i][2] + b4.z; o.w = acc[i][3] + b4.w;
            ((float4*)C)[(size_t)gr * 32 + tc] = o;
        }
    }
}

// ---------------- edge aggregation: one wave per node ----------------
__global__ __launch_bounds__(256) void k_agg(const float* __restrict__ hw,
                                             const int* __restrict__ es,
                                             const float* __restrict__ en,
                                             const int* __restrict__ offs,
                                             const int* __restrict__ cnt,
                                             const float* __restrict__ selfn,
                                             float* __restrict__ agg) {
    int gtid = blockIdx.x * 256 + threadIdx.x;
    int n = gtid >> 6;
    int lane = threadIdx.x & 63;
    if (n >= N_NODES) return;
    const float2* hw2 = (const float2*)hw;
    float sn = selfn[n];
    float2 acc = hw2[(size_t)n * 64 + lane];
    acc.x *= sn; acc.y *= sn;
    int beg = offs[n], num = cnt[n];
    for (int i = 0; i < num; ++i) {
        int s = es[beg + i];
        float w = en[beg + i];
        float2 v = hw2[(size_t)s * 64 + lane];
        acc.x += v.x * w; acc.y += v.y * w;
    }
    ((float2*)agg)[(size_t)n * 64 + lane] = acc;
}

// ---------------- batchnorm stats ----------------
__global__ void k_bnstats(const float* __restrict__ agg, float* colsum, float* colsumsq) {
    __shared__ float s1[256], s2[256];
    int t = threadIdx.x;
    int j = t & 127, half = t >> 7;
    float sum = 0.f, sumsq = 0.f;
    int rowsPerBlock = (N_NODES + gridDim.x - 1) / gridDim.x;
    int r0 = blockIdx.x * rowsPerBlock;
    int r1 = min(r0 + rowsPerBlock, N_NODES);
    for (int r = r0 + half; r < r1; r += 2) {
        float v = agg[(size_t)r * 128 + j];
        sum += v; sumsq += v * v;
    }
    s1[t] = sum; s2[t] = sumsq;
    __syncthreads();
    if (t < 128) {
        sum = s1[t] + s1[t + 128];
        sumsq = s2[t] + s2[t + 128];
        unsafeAtomicAdd(&colsum[t], sum);
        unsafeAtomicAdd(&colsumsq[t], sumsq);
    }
}

__global__ void k_bnfinal(float* colsum, float* colsumsq, float* mean, float* rstd) {
    int j = threadIdx.x;  // 128
    float m = colsum[j] * (1.0f / N_NODES);
    float v = colsumsq[j] * (1.0f / N_NODES) - m * m;
    mean[j] = m;
    rstd[j] = rsqrtf(v + 1e-5f);
    colsum[j] = 0.f;    // ready for next layer
    colsumsq[j] = 0.f;
}

__global__ void k_normrelu(const float* __restrict__ agg, const float* __restrict__ mean,
                           const float* __restrict__ rstd, float* __restrict__ h) {
    int i = blockIdx.x * 256 + threadIdx.x;  // float4 index
    if (i >= N_NODES * 32) return;
    int c = i & 31;
    float4 a = ((const float4*)agg)[i];
    float4 m = ((const float4*)mean)[c];
    float4 rs = ((const float4*)rstd)[c];
    float4 o;
    o.x = fmaxf((a.x - m.x) * rs.x, 0.f);
    o.y = fmaxf((a.y - m.y) * rs.y, 0.f);
    o.z = fmaxf((a.z - m.z) * rs.z, 0.f);
    o.w = fmaxf((a.w - m.w) * rs.w, 0.f);
    ((float4*)h)[i] = o;
}

// ---------------- scoring prep: c0 = x_curr @ W1b + lin1_b ; s = colsum(W1c) ----------------
__global__ void k_prep(const float* __restrict__ h, const int* __restrict__ cid,
                       const float* __restrict__ lin1w, const float* __restrict__ lin1b,
                       float* c0, float* svec) {
    int j = threadIdx.x;  // 128
    int cn = cid[0];
    float acc = lin1b[j];
    for (int k = 0; k < 128; ++k)
        acc += h[(size_t)cn * 128 + k] * lin1w[(size_t)(128 + k) * 128 + j];
    float s = 0.f;
    for (int k = 256; k < 512; ++k) s += lin1w[(size_t)k * 128 + j];
    c0[j] = acc;
    svec[j] = s;
}

// ---------------- scoring GEMM + relu + dot(lin2) ----------------
__global__ __launch_bounds__(256) void k_score(const float* __restrict__ h,
                                               const float* __restrict__ lin1w,  // rows 0..127 = W1a
                                               const float* __restrict__ c0,
                                               const float* __restrict__ svec,
                                               const float* __restrict__ ecn,
                                               const float* __restrict__ lin2w,
                                               const float* __restrict__ lin2b,
                                               float* __restrict__ scores, int nrows) {
    __shared__ float Ws[128 * 128];
    __shared__ float As[32 * 128];
    int t = threadIdx.x;
    const float4* W4 = (const float4*)lin1w;
    float4* Ws4s = (float4*)Ws;
    for (int i = t; i < 128 * 32; i += 256) Ws4s[i] = W4[i];
    int rowBase = blockIdx.x * 32;
    const float4* A4 = (const float4*)h;
    float4* As4s = (float4*)As;
    for (int i = t; i < 32 * 32; i += 256) {
        int r = i >> 5, c = i & 31;
        int gr = rowBase + r;
        As4s[i] = (gr < nrows) ? A4[(size_t)gr * 32 + c] : make_float4(0.f, 0.f, 0.f, 0.f);
    }
    __syncthreads();
    int tc = t & 31, tr = t >> 5;
    float acc[4][4] = {};
    const float4* Ws4 = (const float4*)Ws;
    const float4* As4 = (const float4*)As;
    for (int k = 0; k < 128; k += 4) {
        float4 w0 = Ws4[(k + 0) * 32 + tc];
        float4 w1 = Ws4[(k + 1) * 32 + tc];
        float4 w2 = Ws4[(k + 2) * 32 + tc];
        float4 w3 = Ws4[(k + 3) * 32 + tc];
#pragma unroll
        for (int i = 0; i < 4; ++i) {
            float4 a = As4[(tr * 4 + i) * 32 + (k >> 2)];
            acc[i][0] += a.x * w0.x + a.y * w1.x + a.z * w2.x + a.w * w3.x;
            acc[i][1] += a.x * w0.y + a.y * w1.y + a.z * w2.y + a.w * w3.y;
            acc[i][2] += a.x * w0.z + a.y * w1.z + a.z * w2.z + a.w * w3.z;
            acc[i][3] += a.x * w0.w + a.y * w1.w + a.z * w2.w + a.w * w3.w;
        }
    }
    float4 l2 = ((const float4*)lin2w)[tc];
    float4 c4 = ((const float4*)c0)[tc];
    float4 s4 = ((const float4*)svec)[tc];
    float l2b = lin2b[0];
#pragma unroll
    for (int i = 0; i < 4; ++i) {
        int gr = rowBase + tr * 4 + i;
        float e = (gr < nrows) ? ecn[gr] : 0.f;
        float sum = fmaxf(acc[i][0] + c4.x + e * s4.x, 0.f) * l2.x
                  + fmaxf(acc[i][1] + c4.y + e * s4.y, 0.f) * l2.y
                  + fmaxf(acc[i][2] + c4.z + e * s4.z, 0.f) * l2.z
                  + fmaxf(acc[i][3] + c4.w + e * s4.w, 0.f) * l2.w;
        // reduce across the 32 col-groups (consecutive 32 lanes)
        for (int off = 16; off; off >>= 1) sum += __shfl_down(sum, off, 32);
        if (tc == 0 && gr < nrows) scores[gr] = sum + l2b;
    }
}

// ---------------- partition pooling ----------------
__global__ void k_partition(const float* __restrict__ scores, const float* __restrict__ part,
                            float* out) {
    __shared__ float red[256];
    int t = threadIdx.x;
    int p = t & 31, rg = t >> 5;  // 8 row groups
    float acc = 0.f;
    for (int r = blockIdx.x * 8 + rg; r < N_NODES; r += gridDim.x * 8)
        acc += scores[r] * part[(size_t)r * 32 + p];
    red[t] = acc;
    __syncthreads();
    if (t < 32) {
        float s = 0.f;
        for (int i = 0; i < 8; ++i) s += red[i * 32 + t];
        unsafeAtomicAdd(&out[t], s);
    }
}

// ---------------- host ----------------
extern "C" void kernel_launch(void* const* d_in, const int* in_sizes, int n_in,
                              void* d_out, int out_size, void* d_ws, size_t ws_size,
                              hipStream_t stream) {
    const float* x        = (const float*)d_in[0];
    const int*   eidx     = (const int*)d_in[1];
    const float* ew       = (const float*)d_in[2];
    const float* parts    = (const float*)d_in[3];
    // d_in[4] = node_weights (unused by reference)
    const float* ecn      = (const float*)d_in[5];
    const float* conv_w   = (const float*)d_in[6];
    const float* conv_b   = (const float*)d_in[7];
    const float* lin1_w   = (const float*)d_in[8];
    const float* lin1_b   = (const float*)d_in[9];
    const float* lin2_w   = (const float*)d_in[10];
    const float* lin2_b   = (const float*)d_in[11];
    const int*   cid      = (const int*)d_in[12];

    const int* src = eidx;
    const int* dst = eidx + N_EDGES;

    // workspace layout
    char* p = (char*)d_ws;
    auto alloc = [&](size_t bytes) { char* r = p; p += (bytes + 255) & ~size_t(255); return r; };
    float* deg     = (float*)alloc(NP * 4);
    float* dinv    = (float*)alloc(NP * 4);
    float* selfn   = (float*)alloc(NP * 4);
    float* normv   = (float*)alloc(N_EDGES * 4);
    float* scores  = (float*)alloc(NP * 4);
    float* colsum  = (float*)alloc(128 * 4);
    float* colsumsq= (float*)alloc(128 * 4);
    float* mean    = (float*)alloc(128 * 4);
    float* rstd    = (float*)alloc(128 * 4);
    float* c0      = (float*)alloc(128 * 4);
    float* svec    = (float*)alloc(128 * 4);
    float* hw      = (float*)alloc((size_t)N_NODES * 128 * 4);
    float* agg     = (float*)alloc((size_t)N_NODES * 128 * 4);
    int*   cnt     = (int*)alloc(NP * 4);
    int*   offs    = (int*)alloc(NP * 4);
    int*   fill    = (int*)alloc(NP * 4);
    int*   bsum    = (int*)alloc(256 * 4);
    int*   es      = (int*)alloc(N_EDGES * 4);
    float* en      = (float*)alloc(N_EDGES * 4);

    float* out_head = (float*)d_out;          // partition_scores [32]
    float* hbuf     = (float*)d_out + 32;     // h [N,128] — working h buffer for all layers

    const int EB = (N_EDGES + 255) / 256;     // 3125
    const int NB = (NP + 255) / 256;          // 196

    k_init<<<NB, 256, 0, stream>>>(deg, cnt, fill, colsum, colsumsq, out_head);
    k_deg<<<EB, 256, 0, stream>>>(dst, ew, deg);
    k_dinv<<<NB, 256, 0, stream>>>(deg, dinv, selfn);
    k_normcnt<<<EB, 256, 0, stream>>>(src, dst, ew, dinv, normv, cnt);
    k_scan_partial<<<SCAN_NB, 256, 0, stream>>>(cnt, bsum);
    k_scan_mid<<<1, 256, 0, stream>>>(bsum);
    k_scan_final<<<SCAN_NB, 256, 0, stream>>>(cnt, bsum, offs);
    k_fill<<<EB, 256, 0, stream>>>(src, dst, normv, offs, fill, es, en);

    const int GB = (N_NODES + 31) / 32;       // 1563 gemm blocks
    const int AB = (N_NODES * 64 + 255) / 256;// 12500 agg blocks (1 wave/node)
    const int RB = (N_NODES * 32 + 255) / 256;// 6250 normrelu blocks

    for (int l = 0; l < 3; ++l) {
        const float* hin = (l == 0) ? x : hbuf;
        k_gemm<<<GB, 256, 0, stream>>>(hin, conv_w + (size_t)l * 128 * 128,
                                       conv_b + (size_t)l * 128, hw, N_NODES);
        k_agg<<<AB, 256, 0, stream>>>(hw, es, en, offs, cnt, selfn, agg);
        k_bnstats<<<256, 256, 0, stream>>>(agg, colsum, colsumsq);
        k_bnfinal<<<1, 128, 0, stream>>>(colsum, colsumsq, mean, rstd);
        k_normrelu<<<RB, 256, 0, stream>>>(agg, mean, rstd, hbuf);
    }

    k_prep<<<1, 128, 0, stream>>>(hbuf, cid, lin1_w, lin1_b, c0, svec);
    k_score<<<GB, 256, 0, stream>>>(hbuf, lin1_w, c0, svec, ecn, lin2_w, lin2_b, scores, N_NODES);
    k_partition<<<256, 256, 0, stream>>>(scores, parts, out_head);
}